// Round 9
// baseline (174.724 us; speedup 1.0000x reference)
//
#include <hip/hip_runtime.h>
#include <hip/hip_bf16.h>

typedef unsigned short u16;

// Problem constants
#define BB 4
#define TT 2048
#define DIM 512
#define NH 8
#define DH 64
#define DECAY 0.9f

// Retention chunking
#define CC 64
#define NC 32
#define BHN 32

// Scan chunking: CHS=32, NSC=64
#define CHS 32
#define NSC 64

// GEMM tiling
#define TM 128
#define TN 128
#define BK 64

// retention LDS row stride (u16)
#define SS 72

typedef __attribute__((ext_vector_type(8))) short bf16x8;
typedef __attribute__((ext_vector_type(4))) float f32x4;

__device__ __forceinline__ u16 f2bfu(float f) {
  union { float f; unsigned int u; } c; c.f = f;
  unsigned int u = c.u + 0x7FFFu + ((c.u >> 16) & 1u);  // RNE
  return (u16)(u >> 16);
}
__device__ __forceinline__ float bf2f(u16 u) {
  union { unsigned int u; float f; } c; c.u = ((unsigned int)u) << 16;
  return c.f;
}

__device__ __forceinline__ void gl_lds16(const void* g, void* l) {
  __builtin_amdgcn_global_load_lds(
      (const __attribute__((address_space(1))) void*)g,
      (__attribute__((address_space(3))) void*)(unsigned int)(unsigned long long)l,
      16, 0, 0);
}

// ---------------------------------------------------------------------------
// Double-tile gemm: computes a = sigmoid(q@Wa+ba) AND b = q@Wb+bb for the
// same 128x128 (m,n) range, sharing one A staging (A read once, 32 MFMA per
// barrier pair). Epilogue additionally computes the per-chunk scan aggregates
// (prod a, h_local) inline (from the SAME bf16-rounded values the old part
// pass read) via 4-lane shfl segmented merge, eliminating the part pass.
// ---------------------------------------------------------------------------
__device__ __forceinline__ void gemm_tile_ab(
    int nTile, int mTile, const u16* __restrict__ A,
    const u16* __restrict__ Wta, const u16* __restrict__ Wtb,
    const float* __restrict__ ba, const float* __restrict__ bb,
    u16* __restrict__ Ca, u16* __restrict__ Cb, float2* __restrict__ SAB,
    u16* As, u16* Bsa, u16* Bsb, int tid) {
  int wave = tid >> 6, lane = tid & 63;
  int wm = (wave >> 1) * 64, wn = (wave & 1) * 64;
  int rowA = lane & 15, khalf = lane >> 4;

  f32x4 acca[4][4], accb[4][4];
#pragma unroll
  for (int i = 0; i < 4; ++i)
#pragma unroll
    for (int j = 0; j < 4; ++j) {
      acca[i][j] = (f32x4){0.f, 0.f, 0.f, 0.f};
      accb[i][j] = (f32x4){0.f, 0.f, 0.f, 0.f};
    }

  const u16* Abase = A + (size_t)mTile * TM * 512;
  const u16* BabB = Wta + (size_t)nTile * TN * 512;
  const u16* BbbB = Wtb + (size_t)nTile * TN * 512;

  for (int kk = 0; kk < 512; kk += BK) {
#pragma unroll
    for (int i = 0; i < 4; ++i) {
      int o = (wave * 4 + i) * 64 + lane;
      int row = o >> 3, gk = (o & 7) ^ (row & 7);
      gl_lds16(Abase + (size_t)row * 512 + kk + gk * 8, &As[o * 8]);
    }
#pragma unroll
    for (int i = 0; i < 4; ++i) {
      int o = (wave * 4 + i) * 64 + lane;
      int row = o >> 3, gk = (o & 7) ^ (row & 7);
      gl_lds16(BabB + (size_t)row * 512 + kk + gk * 8, &Bsa[o * 8]);
    }
#pragma unroll
    for (int i = 0; i < 4; ++i) {
      int o = (wave * 4 + i) * 64 + lane;
      int row = o >> 3, gk = (o & 7) ^ (row & 7);
      gl_lds16(BbbB + (size_t)row * 512 + kk + gk * 8, &Bsb[o * 8]);
    }
    __syncthreads();
#pragma unroll
    for (int k0 = 0; k0 < 2; ++k0) {
      bf16x8 af[4], bfa[4], bfb[4];
#pragma unroll
      for (int mi = 0; mi < 4; ++mi) {
        int rr = wm + mi * 16 + rowA;
        int gk = k0 * 4 + khalf;
        int o = rr * 8 + (gk ^ (rr & 7));
        af[mi] = *(const bf16x8*)&As[o * 8];
      }
#pragma unroll
      for (int ni = 0; ni < 4; ++ni) {
        int rr = wn + ni * 16 + rowA;
        int gk = k0 * 4 + khalf;
        int o = rr * 8 + (gk ^ (rr & 7));
        bfa[ni] = *(const bf16x8*)&Bsa[o * 8];
        bfb[ni] = *(const bf16x8*)&Bsb[o * 8];
      }
#pragma unroll
      for (int mi = 0; mi < 4; ++mi)
#pragma unroll
        for (int ni = 0; ni < 4; ++ni) {
          acca[mi][ni] = __builtin_amdgcn_mfma_f32_16x16x32_bf16(
              af[mi], bfa[ni], acca[mi][ni], 0, 0, 0);
          accb[mi][ni] = __builtin_amdgcn_mfma_f32_16x16x32_bf16(
              af[mi], bfb[ni], accb[mi][ni], 0, 0, 0);
        }
    }
    __syncthreads();
  }
  int cloc = lane & 15, q = lane >> 4, rq = q * 4;
  // Per (chunk, ni): write C elements, build 4-lane segments in t-order,
  // shfl-merge to full-chunk (prod, h), lane q==0 stores the aggregate.
#pragma unroll
  for (int chunk = 0; chunk < 2; ++chunk) {
#pragma unroll
    for (int ni = 0; ni < 4; ++ni) {
      int n = nTile * TN + wn + ni * 16 + cloc;
      float pa0 = 1.f, h0 = 0.f, pa1 = 1.f, h1 = 0.f;
#pragma unroll
      for (int half = 0; half < 2; ++half) {
        int mi = chunk * 2 + half;
#pragma unroll
        for (int r = 0; r < 4; ++r) {
          int m = mTile * TM + wm + mi * 16 + rq + r;
          float av = 1.0f / (1.0f + __expf(-(acca[mi][ni][r] + ba[n])));
          float bv = accb[mi][ni][r] + bb[n];
          u16 ua = f2bfu(av), ub = f2bfu(bv);
          Ca[(size_t)m * 512 + n] = ua;
          Cb[(size_t)m * 512 + n] = ub;
          float avr = bf2f(ua), bvr = bf2f(ub);
          if (half == 0) { h0 = fmaf(avr, h0, bvr); pa0 *= avr; }
          else           { h1 = fmaf(avr, h1, bvr); pa1 *= avr; }
        }
      }
      float pas[8], hs[8];
#pragma unroll
      for (int j = 0; j < 4; ++j) {
        int src = cloc + j * 16;
        pas[j] = __shfl(pa0, src);
        hs[j] = __shfl(h0, src);
        pas[4 + j] = __shfl(pa1, src);
        hs[4 + j] = __shfl(h1, src);
      }
      float paT = pas[0], hT = hs[0];
#pragma unroll
      for (int s = 1; s < 8; ++s) {
        hT = fmaf(pas[s], hT, hs[s]);
        paT *= pas[s];
      }
      if (q == 0) {
        int g_ci = mTile * 4 + (wave >> 1) * 2 + chunk;  // global chunk
        SAB[(size_t)(g_ci & 63) * 2048 + (g_ci >> 6) * 512 + n] =
            make_float2(paT, hT);
      }
    }
  }
}

// ---------------------------------------------------------------------------
// Single-tile gemm for g = sigmoid(q@Wg+bg), 128x128.
// ---------------------------------------------------------------------------
__device__ __forceinline__ void gemm_tile_g(
    int nTile, int mTile, const u16* __restrict__ A, const u16* __restrict__ Bt,
    const float* __restrict__ bias, u16* __restrict__ C,
    u16* As, u16* Bs, int tid) {
  int wave = tid >> 6, lane = tid & 63;
  int wm = (wave >> 1) * 64, wn = (wave & 1) * 64;
  int rowA = lane & 15, khalf = lane >> 4;

  f32x4 acc[4][4];
#pragma unroll
  for (int i = 0; i < 4; ++i)
#pragma unroll
    for (int j = 0; j < 4; ++j) acc[i][j] = (f32x4){0.f, 0.f, 0.f, 0.f};

  const u16* Abase = A + (size_t)mTile * TM * 512;
  const u16* Bbase = Bt + (size_t)nTile * TN * 512;

  for (int kk = 0; kk < 512; kk += BK) {
#pragma unroll
    for (int i = 0; i < 4; ++i) {
      int o = (wave * 4 + i) * 64 + lane;
      int row = o >> 3, gk = (o & 7) ^ (row & 7);
      gl_lds16(Abase + (size_t)row * 512 + kk + gk * 8, &As[o * 8]);
    }
#pragma unroll
    for (int i = 0; i < 4; ++i) {
      int o = (wave * 4 + i) * 64 + lane;
      int row = o >> 3, gk = (o & 7) ^ (row & 7);
      gl_lds16(Bbase + (size_t)row * 512 + kk + gk * 8, &Bs[o * 8]);
    }
    __syncthreads();
#pragma unroll
    for (int k0 = 0; k0 < 2; ++k0) {
      bf16x8 af[4], bfr[4];
#pragma unroll
      for (int mi = 0; mi < 4; ++mi) {
        int rr = wm + mi * 16 + rowA;
        int gk = k0 * 4 + khalf;
        int o = rr * 8 + (gk ^ (rr & 7));
        af[mi] = *(const bf16x8*)&As[o * 8];
      }
#pragma unroll
      for (int ni = 0; ni < 4; ++ni) {
        int rr = wn + ni * 16 + rowA;
        int gk = k0 * 4 + khalf;
        int o = rr * 8 + (gk ^ (rr & 7));
        bfr[ni] = *(const bf16x8*)&Bs[o * 8];
      }
#pragma unroll
      for (int mi = 0; mi < 4; ++mi)
#pragma unroll
        for (int ni = 0; ni < 4; ++ni)
          acc[mi][ni] = __builtin_amdgcn_mfma_f32_16x16x32_bf16(
              af[mi], bfr[ni], acc[mi][ni], 0, 0, 0);
    }
    __syncthreads();
  }
  int cloc = lane & 15, rq = (lane >> 4) * 4;
#pragma unroll
  for (int mi = 0; mi < 4; ++mi) {
#pragma unroll
    for (int r = 0; r < 4; ++r) {
      int m = mTile * TM + wm + mi * 16 + rq + r;
#pragma unroll
      for (int ni = 0; ni < 4; ++ni) {
        int n = nTile * TN + wn + ni * 16 + cloc;
        float vv = acc[mi][ni][r] + bias[n];
        vv = 1.0f / (1.0f + __expf(-vv));
        C[(size_t)m * 512 + n] = f2bfu(vv);
      }
    }
  }
}

// ---------------------------------------------------------------------------
// GEMM tile body, TM=128 x TN=64 (gemm2): fp32 out = A@Bt^T + bias + Radd
// ---------------------------------------------------------------------------
__device__ __forceinline__ void gemm_tile64(
    int nTile, int mTile, const u16* __restrict__ A, const u16* __restrict__ Bt,
    const float* __restrict__ bias, float* __restrict__ C,
    const u16* __restrict__ Radd, u16* As, u16* Bs, int tid) {
  int wave = tid >> 6, lane = tid & 63;
  int wm = wave * 32;
  int rowA = lane & 15, khalf = lane >> 4;

  f32x4 acc[2][4];
#pragma unroll
  for (int i = 0; i < 2; ++i)
#pragma unroll
    for (int j = 0; j < 4; ++j) acc[i][j] = (f32x4){0.f, 0.f, 0.f, 0.f};

  const u16* Abase = A + (size_t)mTile * TM * 512;
  const u16* Bbase = Bt + (size_t)nTile * 64 * 512;

  for (int kk = 0; kk < 512; kk += BK) {
#pragma unroll
    for (int i = 0; i < 4; ++i) {
      int o = (wave * 4 + i) * 64 + lane;
      int row = o >> 3, gk = (o & 7) ^ (row & 7);
      gl_lds16(Abase + (size_t)row * 512 + kk + gk * 8, &As[o * 8]);
    }
#pragma unroll
    for (int i = 0; i < 2; ++i) {
      int o = (wave * 2 + i) * 64 + lane;
      int row = o >> 3, gk = (o & 7) ^ (row & 7);
      gl_lds16(Bbase + (size_t)row * 512 + kk + gk * 8, &Bs[o * 8]);
    }
    __syncthreads();
#pragma unroll
    for (int k0 = 0; k0 < 2; ++k0) {
      bf16x8 af[2], bfr[4];
#pragma unroll
      for (int mi = 0; mi < 2; ++mi) {
        int rr = wm + mi * 16 + rowA;
        int gk = k0 * 4 + khalf;
        int o = rr * 8 + (gk ^ (rr & 7));
        af[mi] = *(const bf16x8*)&As[o * 8];
      }
#pragma unroll
      for (int ni = 0; ni < 4; ++ni) {
        int rr = ni * 16 + rowA;
        int gk = k0 * 4 + khalf;
        int o = rr * 8 + (gk ^ (rr & 7));
        bfr[ni] = *(const bf16x8*)&Bs[o * 8];
      }
#pragma unroll
      for (int mi = 0; mi < 2; ++mi)
#pragma unroll
        for (int ni = 0; ni < 4; ++ni)
          acc[mi][ni] = __builtin_amdgcn_mfma_f32_16x16x32_bf16(
              af[mi], bfr[ni], acc[mi][ni], 0, 0, 0);
    }
    __syncthreads();
  }
  int cloc = lane & 15, rq = (lane >> 4) * 4;
#pragma unroll
  for (int mi = 0; mi < 2; ++mi) {
#pragma unroll
    for (int r = 0; r < 4; ++r) {
      int m = mTile * TM + wm + mi * 16 + rq + r;
#pragma unroll
      for (int ni = 0; ni < 4; ++ni) {
        int n = nTile * 64 + ni * 16 + cloc;
        float vv = acc[mi][ni][r] + bias[n] + bf2f(Radd[(size_t)m * 512 + n]);
        C[(size_t)m * 512 + n] = vv;
      }
    }
  }
}

// ---------------------------------------------------------------------------
// Scan family (scalar, deterministic).
// ---------------------------------------------------------------------------
__device__ __forceinline__ void dev_retscan(int unit, int tid,
    const u16* __restrict__ KVTb, u16* __restrict__ Ptb) {
  int gid = unit * 256 + tid;
  int bh = gid >> 12, ed = gid & 4095;
  float carry = 0.f;
  const float dC = __powf(DECAY, (float)CC);
#pragma unroll
  for (int c = 0; c < NC; ++c) {
    size_t idx = ((size_t)(c * BHN + bh)) * 4096 + ed;
    Ptb[idx] = f2bfu(carry);
    carry = fmaf(dC, carry, bf2f(KVTb[idx]));
  }
}

// apply: lookback with 8-wide batched independent loads (R8 win, kept).
__device__ __forceinline__ void dev_apply(int unit, int tid,
    const u16* __restrict__ Ab16, const u16* __restrict__ Bb16,
    const u16* __restrict__ g, const float2* __restrict__ SAB,
    u16* __restrict__ hg) {
  int ci = unit >> 3, grp = unit & 7;
  int ch = grp * 256 + tid;
  int bb = ch >> 9, d = ch & 511;
  float carry = 0.f;
  int p = 0;
  for (; p + 8 <= ci; p += 8) {
    float2 s[8];
#pragma unroll
    for (int j = 0; j < 8; ++j) s[j] = SAB[(size_t)(p + j) * 2048 + ch];
#pragma unroll
    for (int j = 0; j < 8; ++j) carry = fmaf(s[j].x, carry, s[j].y);
  }
  for (; p < ci; ++p) {
    float2 s = SAB[(size_t)p * 2048 + ch];
    carry = fmaf(s.x, carry, s.y);
  }
  size_t base = ((size_t)bb * TT + ci * CHS) * DIM + d;
  float h = carry;
#pragma unroll
  for (int t = 0; t < CHS; ++t) {
    size_t idx = base + (size_t)t * DIM;
    h = fmaf(bf2f(Ab16[idx]), h, bf2f(Bb16[idx]));
    hg[idx] = f2bfu(h * bf2f(g[idx]));
  }
}

// ret_out unit: one (bh, chunk c). S_ij = [q_i.(k_j d^{63-j})] * d^{i-63}.
__device__ __forceinline__ void dev_retout(int unit, int tid,
    u16* Sa, float* dp, float* dpi,
    const u16* __restrict__ qbf, const u16* __restrict__ kcb,
    const u16* __restrict__ VTg, const u16* __restrict__ Ptb,
    u16* __restrict__ routb) {
  int bh = unit & 31, c = unit >> 5;
  int b = bh >> 3, h = bh & 7;
  int wave = tid >> 6, lane = tid & 63;
  size_t base = ((size_t)(b * TT + c * CC)) * DIM + h * DH;
  if (tid < 66) dp[tid] = __powf(DECAY, (float)tid);
  if (tid < 64) dpi[tid] = __powf(DECAY, (float)tid - 63.0f);

  int wm = (wave >> 1) * 32, wn = (wave & 1) * 32;
  int rowA = lane & 15, khalf = lane >> 4;

  bf16x8 afq[2][2];
#pragma unroll
  for (int k0 = 0; k0 < 2; ++k0)
#pragma unroll
    for (int mi = 0; mi < 2; ++mi)
      afq[k0][mi] = *(const bf16x8*)(qbf + base +
          (size_t)(wm + mi * 16 + rowA) * 512 + (k0 * 4 + khalf) * 8);
  const u16* kcbase = kcb + ((size_t)bh * NC + c) * 64 * 64;
  bf16x8 bfk[2][2];
#pragma unroll
  for (int k0 = 0; k0 < 2; ++k0)
#pragma unroll
    for (int ni = 0; ni < 2; ++ni)
      bfk[k0][ni] = *(const bf16x8*)(kcbase +
          (size_t)(wn + ni * 16 + rowA) * 64 + (k0 * 4 + khalf) * 8);

  f32x4 accS[2][2];
#pragma unroll
  for (int i = 0; i < 2; ++i)
#pragma unroll
    for (int j = 0; j < 2; ++j) accS[i][j] = (f32x4){0.f, 0.f, 0.f, 0.f};
#pragma unroll
  for (int k0 = 0; k0 < 2; ++k0)
#pragma unroll
    for (int mi = 0; mi < 2; ++mi)
#pragma unroll
      for (int ni = 0; ni < 2; ++ni)
        accS[mi][ni] = __builtin_amdgcn_mfma_f32_16x16x32_bf16(
            afq[k0][mi], bfk[k0][ni], accS[mi][ni], 0, 0, 0);
  __syncthreads();  // dp/dpi ready

  int cloc = lane & 15, rq = (lane >> 4) * 4;
#pragma unroll
  for (int mi = 0; mi < 2; ++mi)
#pragma unroll
    for (int ni = 0; ni < 2; ++ni)
#pragma unroll
      for (int r = 0; r < 4; ++r) {
        int i = wm + mi * 16 + rq + r;
        int j = wn + ni * 16 + cloc;
        float sv = (j <= i) ? accS[mi][ni][r] * dpi[i] : 0.f;
        Sa[i * SS + j] = f2bfu(sv);
      }
#pragma unroll
  for (int mi = 0; mi < 2; ++mi) {
    float s = dp[wm + mi * 16 + rowA + 1];
#pragma unroll
    for (int k0 = 0; k0 < 2; ++k0) {
      bf16x8 t = afq[k0][mi];
#pragma unroll
      for (int u = 0; u < 8; ++u)
        t[u] = (short)f2bfu(bf2f((u16)t[u]) * s);
      afq[k0][mi] = t;
    }
  }
  __syncthreads();  // Sa ready

  f32x4 accO[2][2];
#pragma unroll
  for (int i = 0; i < 2; ++i)
#pragma unroll
    for (int j = 0; j < 2; ++j) accO[i][j] = (f32x4){0.f, 0.f, 0.f, 0.f};
#pragma unroll
  for (int k0 = 0; k0 < 4; ++k0) {
    bf16x8 af[2], bfv[2];
#pragma unroll
    for (int mi = 0; mi < 2; ++mi) {
      if (k0 < 2)
        af[mi] = *(const bf16x8*)&Sa[(wm + mi * 16 + rowA) * SS +
                                     (k0 * 4 + khalf) * 8];
      else
        af[mi] = afq[k0 - 2][mi];
    }
#pragma unroll
    for (int ni = 0; ni < 2; ++ni) {
      int e = wn + ni * 16 + rowA;
      if (k0 < 2)
        bfv[ni] = *(const bf16x8*)(VTg + ((size_t)bh * 64 + e) * TT + c * 64 +
                                   (k0 * 4 + khalf) * 8);
      else
        bfv[ni] = *(const bf16x8*)(Ptb + ((size_t)(c * BHN + bh)) * 4096 +
                                   e * 64 + ((k0 - 2) * 4 + khalf) * 8);
    }
#pragma unroll
    for (int mi = 0; mi < 2; ++mi)
#pragma unroll
      for (int ni = 0; ni < 2; ++ni)
        accO[mi][ni] = __builtin_amdgcn_mfma_f32_16x16x32_bf16(
            af[mi], bfv[ni], accO[mi][ni], 0, 0, 0);
  }
#pragma unroll
  for (int mi = 0; mi < 2; ++mi)
#pragma unroll
    for (int r = 0; r < 4; ++r) {
      int i = wm + mi * 16 + rq + r;
#pragma unroll
      for (int ni = 0; ni < 2; ++ni) {
        int e = wn + ni * 16 + cloc;
        routb[base + (size_t)i * 512 + e] = f2bfu(accO[mi][ni][r]);
      }
    }
}

// ---------------------------------------------------------------------------
// K1: [0,1024) ret_kv (+kcb); [1024,2048) wtrans; [2048,4096) cvt q (2x).
// ---------------------------------------------------------------------------
__global__ __launch_bounds__(256) void k1_prep_retkv(
    const float* __restrict__ q, u16* __restrict__ qbf,
    const float* __restrict__ W0, const float* __restrict__ W1,
    const float* __restrict__ W2, const float* __restrict__ W3,
    u16* __restrict__ Wt,
    const float* __restrict__ k, const float* __restrict__ v,
    u16* __restrict__ KVTb, u16* __restrict__ VTg, u16* __restrict__ kcb) {
  __shared__ __align__(16) u16 smem[2 * 64 * SS];  // retkv VT+KT (18.4 KB)
  __shared__ float t[32][33];                      // wtrans (4.2 KB)
  int bx = blockIdx.x, tid = threadIdx.x;
  if (bx < 1024) {
    // ---- ret_kv ----
    int bh = bx & 31, c = bx >> 5;
    int b = bh >> 3, h = bh & 7;
    int wave = tid >> 6, lane = tid & 63;
    u16* VT = smem;
    u16* KT = smem + 64 * SS;
    size_t base = ((size_t)(b * TT + c * CC)) * DIM + h * DH;
    int row = tid >> 2, part = tid & 3, e0 = part * 16;
    float w = __powf(DECAY, (float)(63 - row));
    __align__(16) u16 krow[16];
    {
      const float4* vs = (const float4*)(v + base + (size_t)row * DIM + e0);
      const float4* ks = (const float4*)(k + base + (size_t)row * DIM + e0);
#pragma unroll
      for (int u4 = 0; u4 < 4; ++u4) {
        float4 fv = vs[u4], fk = ks[u4];
        VT[(e0 + u4 * 4 + 0) * SS + row] = f2bfu(fv.x);
        VT[(e0 + u4 * 4 + 1) * SS + row] = f2bfu(fv.y);
        VT[(e0 + u4 * 4 + 2) * SS + row] = f2bfu(fv.z);
        VT[(e0 + u4 * 4 + 3) * SS + row] = f2bfu(fv.w);
        u16 k0s = f2bfu(fk.x * w), k1s = f2bfu(fk.y * w);
        u16 k2s = f2bfu(fk.z * w), k3s = f2bfu(fk.w * w);
        KT[(e0 + u4 * 4 + 0) * SS + row] = k0s;
        KT[(e0 + u4 * 4 + 1) * SS + row] = k1s;
        KT[(e0 + u4 * 4 + 2) * SS + row] = k2s;
        KT[(e0 + u4 * 4 + 3) * SS + row] = k3s;
        krow[u4 * 4 + 0] = k0s; krow[u4 * 4 + 1] = k1s;
        krow[u4 * 4 + 2] = k2s; krow[u4 * 4 + 3] = k3s;
      }
    }
    {  // write scaled-K row-major compact (t-major)
      u16* kdst = kcb + (((size_t)bh * NC + c) * 64 + row) * 64 + e0;
      *(uint4*)kdst = *(const uint4*)&krow[0];
      *(uint4*)(kdst + 8) = *(const uint4*)&krow[8];
    }
    __syncthreads();
    {
      int e = row;
      u16* dst = VTg + ((size_t)bh * 64 + e) * TT + c * 64 + part * 16;
      *(uint4*)dst = *(const uint4*)&VT[e * SS + part * 16];
      *(uint4*)(dst + 8) = *(const uint4*)&VT[e * SS + part * 16 + 8];
    }
    int wm = (wave >> 1) * 32, wn = (wave & 1) * 32;
    int rowA = lane & 15, khalf = lane >> 4;
    f32x4 acc[2][2];
#pragma unroll
    for (int i = 0; i < 2; ++i)
#pragma unroll
      for (int j = 0; j < 2; ++j) acc[i][j] = (f32x4){0.f, 0.f, 0.f, 0.f};
#pragma unroll
    for (int k0 = 0; k0 < 2; ++k0) {
      int gk = k0 * 4 + khalf;
      bf16x8 af[2], bfr[2];
#pragma unroll
      for (int mi = 0; mi < 2; ++mi)
        af[mi] = *(const bf16x8*)&VT[(wm + mi * 16 + rowA) * SS + gk * 8];
#pragma unroll
      for (int ni = 0; ni < 2; ++ni)
        bfr[ni] = *(const bf16x8*)&KT[(wn + ni * 16 + rowA) * SS + gk * 8];
#pragma unroll
      for (int mi = 0; mi < 2; ++mi)
#pragma unroll
        for (int ni = 0; ni < 2; ++ni)
          acc[mi][ni] = __builtin_amdgcn_mfma_f32_16x16x32_bf16(
              af[mi], bfr[ni], acc[mi][ni], 0, 0, 0);
    }
    int cloc = lane & 15, rq = (lane >> 4) * 4;
    u16* o = KVTb + ((size_t)(c * BHN + bh)) * 4096;
#pragma unroll
    for (int mi = 0; mi < 2; ++mi)
#pragma unroll
      for (int r = 0; r < 4; ++r) {
        int e = wm + mi * 16 + rq + r;
#pragma unroll
        for (int ni = 0; ni < 2; ++ni)
          o[e * 64 + (wn + ni * 16 + cloc)] = f2bfu(acc[mi][ni][r]);
      }
  } else if (bx < 2048) {
    // ---- wtrans ----
    int bx2 = bx - 1024;
    int m = bx2 >> 8, rem = bx2 & 255;
    int n0 = (rem & 15) * 32, k0 = (rem >> 4) * 32;
    const float* W = (m == 0) ? W0 : (m == 1) ? W1 : (m == 2) ? W2 : W3;
    int tx = tid & 31, ty = tid >> 5;
#pragma unroll
    for (int r = 0; r < 32; r += 8)
      t[ty + r][tx] = W[(size_t)(k0 + ty + r) * DIM + n0 + tx];
    __syncthreads();
    u16* o = Wt + (size_t)m * DIM * DIM;
#pragma unroll
    for (int r = 0; r < 32; r += 8)
      o[(size_t)(n0 + ty + r) * DIM + k0 + tx] = f2bfu(t[tx][ty + r]);
  } else {
    // ---- cvt q (2 float4 per thread) ----
    int i0 = ((bx - 2048) * 256 + tid) * 2;
#pragma unroll
    for (int u2 = 0; u2 < 2; ++u2) {
      float4 f = ((const float4*)q)[i0 + u2];
      ushort4 u;
      u.x = f2bfu(f.x); u.y = f2bfu(f.y); u.z = f2bfu(f.z); u.w = f2bfu(f.w);
      ((ushort4*)qbf)[i0 + u2] = u;
    }
  }
}

// ---------------------------------------------------------------------------
// K2: [0,256) gemm1-ab double-tiles (4 nT x 64 mT, XCD swizzle);
//     [256,512) gemm1-g tiles; [512,1024) retscan.
// ---------------------------------------------------------------------------
__global__ __launch_bounds__(256) void k2_gemm1_retscan(
    const u16* __restrict__ qbf, const u16* __restrict__ WtAll,
    const float* __restrict__ ba, const float* __restrict__ bb,
    const float* __restrict__ bg,
    u16* __restrict__ Ab16, u16* __restrict__ Bb16, u16* __restrict__ Gb16,
    float2* __restrict__ SAB,
    const u16* __restrict__ KVTb, u16* __restrict__ Ptb) {
  __shared__ __align__(16) u16 smem[3 * TM * BK];  // 48 KB (A + Ba + Bb)
  int bx = blockIdx.x, tid = threadIdx.x;
  if (bx < 256) {
    // bijective: bx = r + 8*(nT + 4*s), mT = s*8 + r (r<8, nT<4, s<8)
    int r = bx & 7, t6 = bx >> 3;
    int nT = t6 & 3, s = t6 >> 2;
    int mT = (s << 3) | r;
    gemm_tile_ab(nT, mT, qbf, WtAll, WtAll + 512 * 512, ba, bb,
                 Ab16, Bb16, SAB, smem, smem + TM * BK, smem + 2 * TM * BK,
                 tid);
  } else if (bx < 512) {
    int bx2 = bx - 256;
    int r = bx2 & 7, t6 = bx2 >> 3;
    int nT = t6 & 3, s = t6 >> 2;
    int mT = (s << 3) | r;
    gemm_tile_g(nT, mT, qbf, WtAll + 2 * 512 * 512, bg, Gb16,
                smem, smem + TM * BK, tid);
  } else {
    dev_retscan(bx - 512, tid, KVTb, Ptb);
  }
}

// ---------------------------------------------------------------------------
// K3: [0,512) scan_apply HIGH-ci FIRST; [512,1536) ret_out (all 1024 units).
// ---------------------------------------------------------------------------
__global__ __launch_bounds__(256) void k3_apply_retout(
    const u16* __restrict__ Ab16, const u16* __restrict__ Bb16,
    const u16* __restrict__ g, const float2* __restrict__ SAB,
    u16* __restrict__ hg,
    const u16* __restrict__ qbf, const u16* __restrict__ kcb,
    const u16* __restrict__ VTg, const u16* __restrict__ Ptb,
    u16* __restrict__ routb) {
  __shared__ __align__(16) u16 Sa[64 * SS];
  __shared__ float dp[66];
  __shared__ float dpi[64];
  int bx = blockIdx.x, tid = threadIdx.x;
  if (bx < 512) {
    dev_apply(511 - bx, tid, Ab16, Bb16, g, SAB, hg);
    return;
  }
  dev_retout(bx - 512, tid, Sa, dp, dpi, qbf, kcb, VTg, Ptb, routb);
}

// ---------------------------------------------------------------------------
// K4: gemm2 (512 blocks, TN=64): out = (h*g) @ Wo + bo + r_out
// ---------------------------------------------------------------------------
__global__ __launch_bounds__(256) void k4_gemm2(
    const u16* __restrict__ hgbf, const u16* __restrict__ Wto,
    const float* __restrict__ bo, float* __restrict__ out,
    const u16* __restrict__ routb) {
  __shared__ __align__(16) u16 smem[TM * BK + 64 * BK];  // 24 KB
  int bx = blockIdx.x;
  // bijective: bx = r + 8*(nT + 8*s), mT = s*8 + r  (r<8, s<8, nT<8)
  int r = bx & 7, t6 = bx >> 3;
  int nT = t6 & 7, s = t6 >> 3;
  int mT = (s << 3) | r;
  gemm_tile64(nT, mT, hgbf, Wto, bo, out, routb,
              smem, smem + TM * BK, threadIdx.x);
}

// ---------------------------------------------------------------------------
extern "C" void kernel_launch(void* const* d_in, const int* in_sizes, int n_in,
                              void* d_out, int out_size, void* d_ws, size_t ws_size,
                              hipStream_t stream) {
  const float* q  = (const float*)d_in[0];
  const float* k  = (const float*)d_in[1];
  const float* v  = (const float*)d_in[2];
  const float* Wa = (const float*)d_in[3];
  const float* ba = (const float*)d_in[4];
  const float* Wb = (const float*)d_in[5];
  const float* bb = (const float*)d_in[6];
  const float* Wg = (const float*)d_in[7];
  const float* bg = (const float*)d_in[8];
  const float* Wo = (const float*)d_in[9];
  const float* bo = (const float*)d_in[10];
  float* out = (float*)d_out;

  const size_t NEL = (size_t)BB * TT * DIM;  // 4,194,304
  float2* SAB = (float2*)d_ws;               // 64 chunks x 2048 cols = 1 MB
  u16* up = (u16*)(SAB + (size_t)NSC * 2048);
  u16* Ab16  = up;  up += NEL;               // a bf16
  u16* Bb16  = up;  up += NEL;               // b bf16
  u16* Gb16  = up;  up += NEL;               // g bf16
  u16* qbf   = up;  up += NEL;               // q bf16
  u16* hgbf  = up;  up += NEL;               // h*g bf16
  u16* WtAll = up;  up += 4 * DIM * DIM;     // W^T bf16
  u16* KVTb  = up;  up += (size_t)NC * BHN * 4096;
  u16* Ptb   = up;  up += (size_t)NC * BHN * 4096;
  u16* VTg   = up;  up += (size_t)BHN * 64 * TT;
  u16* routb = up;  up += NEL;               // r_out bf16
  u16* kcb   = up;  up += (size_t)BHN * NC * 64 * 64;  // scaled K bf16, 8 MB

  k1_prep_retkv<<<4096, 256, 0, stream>>>(q, qbf, Wa, Wb, Wg, Wo, WtAll,
                                          k, v, KVTb, VTg, kcb);

  k2_gemm1_retscan<<<1024, 256, 0, stream>>>(qbf, WtAll, ba, bb, bg,
                                             Ab16, Bb16, Gb16, SAB,
                                             KVTb, Ptb);

  k3_apply_retout<<<1536, 256, 0, stream>>>(Ab16, Bb16, Gb16, SAB, hgbf,
                                            qbf, kcb, VTg, Ptb, routb);

  k4_gemm2<<<512, 256, 0, stream>>>(hgbf, WtAll + 3 * DIM * DIM,
                                    bo, out, routb);
}

// Round 10
// 163.335 us; speedup vs baseline: 1.0697x; 1.0697x over previous
//
#include <hip/hip_runtime.h>
#include <hip/hip_bf16.h>

typedef unsigned short u16;

// Problem constants
#define BB 4
#define TT 2048
#define DIM 512
#define NH 8
#define DH 64
#define DECAY 0.9f

// Retention chunking
#define CC 64
#define NC 32
#define BHN 32

// Scan chunking: CHS=32, NSC=64
#define CHS 32
#define NSC 64

// GEMM tiling
#define TM 128
#define TN 128
#define BK 64

// retention LDS row stride (u16)
#define SS 72

typedef __attribute__((ext_vector_type(8))) short bf16x8;
typedef __attribute__((ext_vector_type(4))) float f32x4;

__device__ __forceinline__ u16 f2bfu(float f) {
  union { float f; unsigned int u; } c; c.f = f;
  unsigned int u = c.u + 0x7FFFu + ((c.u >> 16) & 1u);  // RNE
  return (u16)(u >> 16);
}
__device__ __forceinline__ float bf2f(u16 u) {
  union { unsigned int u; float f; } c; c.u = ((unsigned int)u) << 16;
  return c.f;
}

__device__ __forceinline__ void gl_lds16(const void* g, void* l) {
  __builtin_amdgcn_global_load_lds(
      (const __attribute__((address_space(1))) void*)g,
      (__attribute__((address_space(3))) void*)(unsigned int)(unsigned long long)l,
      16, 0, 0);
}

// ---------------------------------------------------------------------------
// GEMM tile body, TM=128 x TN=128 (m97 structure), bf16 outputs. (R8 version)
// ---------------------------------------------------------------------------
__device__ __forceinline__ void gemm_tile(
    int nTile, int mTile, const u16* __restrict__ A, const u16* __restrict__ Bt,
    const float* __restrict__ b0, const float* __restrict__ b1,
    const float* __restrict__ b2,
    u16* __restrict__ C0, u16* __restrict__ C1, u16* __restrict__ C2,
    int act_mask, u16* As, u16* Bs, int tid) {
  int wave = tid >> 6, lane = tid & 63;
  int group = (nTile * TN) >> 9;
  const float* bias = (group == 0) ? b0 : (group == 1) ? b1 : b2;
  u16* C = (group == 0) ? C0 : (group == 1) ? C1 : C2;
  int act = (act_mask >> group) & 1;

  int wm = (wave >> 1) * 64, wn = (wave & 1) * 64;
  int rowA = lane & 15, khalf = lane >> 4;

  f32x4 acc[4][4];
#pragma unroll
  for (int i = 0; i < 4; ++i)
#pragma unroll
    for (int j = 0; j < 4; ++j) acc[i][j] = (f32x4){0.f, 0.f, 0.f, 0.f};

  const u16* Abase = A + (size_t)mTile * TM * 512;
  const u16* Bbase = Bt + (size_t)nTile * TN * 512;

  for (int kk = 0; kk < 512; kk += BK) {
#pragma unroll
    for (int i = 0; i < 4; ++i) {
      int o = (wave * 4 + i) * 64 + lane;
      int row = o >> 3, gk = (o & 7) ^ (row & 7);
      gl_lds16(Abase + (size_t)row * 512 + kk + gk * 8, &As[o * 8]);
    }
#pragma unroll
    for (int i = 0; i < 4; ++i) {
      int o = (wave * 4 + i) * 64 + lane;
      int row = o >> 3, gk = (o & 7) ^ (row & 7);
      gl_lds16(Bbase + (size_t)row * 512 + kk + gk * 8, &Bs[o * 8]);
    }
    __syncthreads();
#pragma unroll
    for (int k0 = 0; k0 < 2; ++k0) {
      bf16x8 af[4], bfr[4];
#pragma unroll
      for (int mi = 0; mi < 4; ++mi) {
        int rr = wm + mi * 16 + rowA;
        int gk = k0 * 4 + khalf;
        int o = rr * 8 + (gk ^ (rr & 7));
        af[mi] = *(const bf16x8*)&As[o * 8];
      }
#pragma unroll
      for (int ni = 0; ni < 4; ++ni) {
        int rr = wn + ni * 16 + rowA;
        int gk = k0 * 4 + khalf;
        int o = rr * 8 + (gk ^ (rr & 7));
        bfr[ni] = *(const bf16x8*)&Bs[o * 8];
      }
#pragma unroll
      for (int mi = 0; mi < 4; ++mi)
#pragma unroll
        for (int ni = 0; ni < 4; ++ni)
          acc[mi][ni] = __builtin_amdgcn_mfma_f32_16x16x32_bf16(
              af[mi], bfr[ni], acc[mi][ni], 0, 0, 0);
    }
    __syncthreads();
  }
  int cloc = lane & 15, rq = (lane >> 4) * 4;
#pragma unroll
  for (int mi = 0; mi < 4; ++mi) {
#pragma unroll
    for (int r = 0; r < 4; ++r) {
      int m = mTile * TM + wm + mi * 16 + rq + r;
#pragma unroll
      for (int ni = 0; ni < 4; ++ni) {
        int n = (nTile * TN + wn + ni * 16 + cloc) & 511;
        float vv = acc[mi][ni][r] + bias[n];
        if (act) vv = 1.0f / (1.0f + __expf(-vv));
        C[(size_t)m * 512 + n] = f2bfu(vv);
      }
    }
  }
}

// ---------------------------------------------------------------------------
// GEMM tile body, TM=128 x TN=64 (gemm2): fp32 out = A@Bt^T + bias + Radd
// ---------------------------------------------------------------------------
__device__ __forceinline__ void gemm_tile64(
    int nTile, int mTile, const u16* __restrict__ A, const u16* __restrict__ Bt,
    const float* __restrict__ bias, float* __restrict__ C,
    const u16* __restrict__ Radd, u16* As, u16* Bs, int tid) {
  int wave = tid >> 6, lane = tid & 63;
  int wm = wave * 32;
  int rowA = lane & 15, khalf = lane >> 4;

  f32x4 acc[2][4];
#pragma unroll
  for (int i = 0; i < 2; ++i)
#pragma unroll
    for (int j = 0; j < 4; ++j) acc[i][j] = (f32x4){0.f, 0.f, 0.f, 0.f};

  const u16* Abase = A + (size_t)mTile * TM * 512;
  const u16* Bbase = Bt + (size_t)nTile * 64 * 512;

  for (int kk = 0; kk < 512; kk += BK) {
#pragma unroll
    for (int i = 0; i < 4; ++i) {
      int o = (wave * 4 + i) * 64 + lane;
      int row = o >> 3, gk = (o & 7) ^ (row & 7);
      gl_lds16(Abase + (size_t)row * 512 + kk + gk * 8, &As[o * 8]);
    }
#pragma unroll
    for (int i = 0; i < 2; ++i) {
      int o = (wave * 2 + i) * 64 + lane;
      int row = o >> 3, gk = (o & 7) ^ (row & 7);
      gl_lds16(Bbase + (size_t)row * 512 + kk + gk * 8, &Bs[o * 8]);
    }
    __syncthreads();
#pragma unroll
    for (int k0 = 0; k0 < 2; ++k0) {
      bf16x8 af[2], bfr[4];
#pragma unroll
      for (int mi = 0; mi < 2; ++mi) {
        int rr = wm + mi * 16 + rowA;
        int gk = k0 * 4 + khalf;
        int o = rr * 8 + (gk ^ (rr & 7));
        af[mi] = *(const bf16x8*)&As[o * 8];
      }
#pragma unroll
      for (int ni = 0; ni < 4; ++ni) {
        int rr = ni * 16 + rowA;
        int gk = k0 * 4 + khalf;
        int o = rr * 8 + (gk ^ (rr & 7));
        bfr[ni] = *(const bf16x8*)&Bs[o * 8];
      }
#pragma unroll
      for (int mi = 0; mi < 2; ++mi)
#pragma unroll
        for (int ni = 0; ni < 4; ++ni)
          acc[mi][ni] = __builtin_amdgcn_mfma_f32_16x16x32_bf16(
              af[mi], bfr[ni], acc[mi][ni], 0, 0, 0);
    }
    __syncthreads();
  }
  int cloc = lane & 15, rq = (lane >> 4) * 4;
#pragma unroll
  for (int mi = 0; mi < 2; ++mi) {
#pragma unroll
    for (int r = 0; r < 4; ++r) {
      int m = mTile * TM + wm + mi * 16 + rq + r;
#pragma unroll
      for (int ni = 0; ni < 4; ++ni) {
        int n = nTile * 64 + ni * 16 + cloc;
        float vv = acc[mi][ni][r] + bias[n] + bf2f(Radd[(size_t)m * 512 + n]);
        C[(size_t)m * 512 + n] = vv;
      }
    }
  }
}

// ---------------------------------------------------------------------------
// Scan family (scalar, deterministic; R8 versions).
// ---------------------------------------------------------------------------
__device__ __forceinline__ void dev_retscan(int unit, int tid,
    const u16* __restrict__ KVTb, u16* __restrict__ Ptb) {
  int gid = unit * 256 + tid;
  int bh = gid >> 12, ed = gid & 4095;
  float carry = 0.f;
  const float dC = __powf(DECAY, (float)CC);
#pragma unroll
  for (int c = 0; c < NC; ++c) {
    size_t idx = ((size_t)(c * BHN + bh)) * 4096 + ed;
    Ptb[idx] = f2bfu(carry);
    carry = fmaf(dC, carry, bf2f(KVTb[idx]));
  }
}

// part: packed (pA, h) float2 aggregate per (chunk, column).
__device__ __forceinline__ void dev_part(int unit, int tid,
    const u16* __restrict__ Ab16, const u16* __restrict__ Bb16,
    float2* __restrict__ SAB) {
  int ci = unit >> 3, grp = unit & 7;
  int ch = grp * 256 + tid;
  int bb2 = ch >> 9, d = ch & 511;
  size_t base = ((size_t)bb2 * TT + ci * CHS) * DIM + d;
  float h = 0.f, pA = 1.f;
#pragma unroll
  for (int t = 0; t < CHS; ++t) {
    float av = bf2f(Ab16[base + (size_t)t * DIM]);
    float bv = bf2f(Bb16[base + (size_t)t * DIM]);
    h = fmaf(av, h, bv);
    pA *= av;
  }
  SAB[(size_t)ci * 2048 + ch] = make_float2(pA, h);
}

// apply: lookback with 8-wide batched independent loads (R8 win, kept).
__device__ __forceinline__ void dev_apply(int unit, int tid,
    const u16* __restrict__ Ab16, const u16* __restrict__ Bb16,
    const u16* __restrict__ g, const float2* __restrict__ SAB,
    u16* __restrict__ hg) {
  int ci = unit >> 3, grp = unit & 7;
  int ch = grp * 256 + tid;
  int bb = ch >> 9, d = ch & 511;
  float carry = 0.f;
  int p = 0;
  for (; p + 8 <= ci; p += 8) {
    float2 s[8];
#pragma unroll
    for (int j = 0; j < 8; ++j) s[j] = SAB[(size_t)(p + j) * 2048 + ch];
#pragma unroll
    for (int j = 0; j < 8; ++j) carry = fmaf(s[j].x, carry, s[j].y);
  }
  for (; p < ci; ++p) {
    float2 s = SAB[(size_t)p * 2048 + ch];
    carry = fmaf(s.x, carry, s.y);
  }
  size_t base = ((size_t)bb * TT + ci * CHS) * DIM + d;
  float h = carry;
#pragma unroll
  for (int t = 0; t < CHS; ++t) {
    size_t idx = base + (size_t)t * DIM;
    h = fmaf(bf2f(Ab16[idx]), h, bf2f(Bb16[idx]));
    hg[idx] = f2bfu(h * bf2f(g[idx]));
  }
}

// ret_out unit: one (bh, chunk c). S_ij = [q_i.(k_j d^{63-j})] * d^{i-63}.
__device__ __forceinline__ void dev_retout(int unit, int tid,
    u16* Sa, float* dp, float* dpi,
    const u16* __restrict__ qbf, const u16* __restrict__ kcb,
    const u16* __restrict__ VTg, const u16* __restrict__ Ptb,
    u16* __restrict__ routb) {
  int bh = unit & 31, c = unit >> 5;
  int b = bh >> 3, h = bh & 7;
  int wave = tid >> 6, lane = tid & 63;
  size_t base = ((size_t)(b * TT + c * CC)) * DIM + h * DH;
  if (tid < 66) dp[tid] = __powf(DECAY, (float)tid);
  if (tid < 64) dpi[tid] = __powf(DECAY, (float)tid - 63.0f);

  int wm = (wave >> 1) * 32, wn = (wave & 1) * 32;
  int rowA = lane & 15, khalf = lane >> 4;

  bf16x8 afq[2][2];
#pragma unroll
  for (int k0 = 0; k0 < 2; ++k0)
#pragma unroll
    for (int mi = 0; mi < 2; ++mi)
      afq[k0][mi] = *(const bf16x8*)(qbf + base +
          (size_t)(wm + mi * 16 + rowA) * 512 + (k0 * 4 + khalf) * 8);
  const u16* kcbase = kcb + ((size_t)bh * NC + c) * 64 * 64;
  bf16x8 bfk[2][2];
#pragma unroll
  for (int k0 = 0; k0 < 2; ++k0)
#pragma unroll
    for (int ni = 0; ni < 2; ++ni)
      bfk[k0][ni] = *(const bf16x8*)(kcbase +
          (size_t)(wn + ni * 16 + rowA) * 64 + (k0 * 4 + khalf) * 8);

  f32x4 accS[2][2];
#pragma unroll
  for (int i = 0; i < 2; ++i)
#pragma unroll
    for (int j = 0; j < 2; ++j) accS[i][j] = (f32x4){0.f, 0.f, 0.f, 0.f};
#pragma unroll
  for (int k0 = 0; k0 < 2; ++k0)
#pragma unroll
    for (int mi = 0; mi < 2; ++mi)
#pragma unroll
      for (int ni = 0; ni < 2; ++ni)
        accS[mi][ni] = __builtin_amdgcn_mfma_f32_16x16x32_bf16(
            afq[k0][mi], bfk[k0][ni], accS[mi][ni], 0, 0, 0);
  __syncthreads();  // dp/dpi ready

  int cloc = lane & 15, rq = (lane >> 4) * 4;
#pragma unroll
  for (int mi = 0; mi < 2; ++mi)
#pragma unroll
    for (int ni = 0; ni < 2; ++ni)
#pragma unroll
      for (int r = 0; r < 4; ++r) {
        int i = wm + mi * 16 + rq + r;
        int j = wn + ni * 16 + cloc;
        float sv = (j <= i) ? accS[mi][ni][r] * dpi[i] : 0.f;
        Sa[i * SS + j] = f2bfu(sv);
      }
#pragma unroll
  for (int mi = 0; mi < 2; ++mi) {
    float s = dp[wm + mi * 16 + rowA + 1];
#pragma unroll
    for (int k0 = 0; k0 < 2; ++k0) {
      bf16x8 t = afq[k0][mi];
#pragma unroll
      for (int u = 0; u < 8; ++u)
        t[u] = (short)f2bfu(bf2f((u16)t[u]) * s);
      afq[k0][mi] = t;
    }
  }
  __syncthreads();  // Sa ready

  f32x4 accO[2][2];
#pragma unroll
  for (int i = 0; i < 2; ++i)
#pragma unroll
    for (int j = 0; j < 2; ++j) accO[i][j] = (f32x4){0.f, 0.f, 0.f, 0.f};
#pragma unroll
  for (int k0 = 0; k0 < 4; ++k0) {
    bf16x8 af[2], bfv[2];
#pragma unroll
    for (int mi = 0; mi < 2; ++mi) {
      if (k0 < 2)
        af[mi] = *(const bf16x8*)&Sa[(wm + mi * 16 + rowA) * SS +
                                     (k0 * 4 + khalf) * 8];
      else
        af[mi] = afq[k0 - 2][mi];
    }
#pragma unroll
    for (int ni = 0; ni < 2; ++ni) {
      int e = wn + ni * 16 + rowA;
      if (k0 < 2)
        bfv[ni] = *(const bf16x8*)(VTg + ((size_t)bh * 64 + e) * TT + c * 64 +
                                   (k0 * 4 + khalf) * 8);
      else
        bfv[ni] = *(const bf16x8*)(Ptb + ((size_t)(c * BHN + bh)) * 4096 +
                                   e * 64 + ((k0 - 2) * 4 + khalf) * 8);
    }
#pragma unroll
    for (int mi = 0; mi < 2; ++mi)
#pragma unroll
      for (int ni = 0; ni < 2; ++ni)
        accO[mi][ni] = __builtin_amdgcn_mfma_f32_16x16x32_bf16(
            af[mi], bfv[ni], accO[mi][ni], 0, 0, 0);
  }
#pragma unroll
  for (int mi = 0; mi < 2; ++mi)
#pragma unroll
    for (int r = 0; r < 4; ++r) {
      int i = wm + mi * 16 + rq + r;
#pragma unroll
      for (int ni = 0; ni < 2; ++ni) {
        int e = wn + ni * 16 + cloc;
        routb[base + (size_t)i * 512 + e] = f2bfu(accO[mi][ni][r]);
      }
    }
}

// ---------------------------------------------------------------------------
// K0: [0,1024) wtrans; [1024,3072) cvt q (2 float4/thread).
// Pure input->ws prep; unblocks gemm1 to co-run with ret_kv in K1.
// ---------------------------------------------------------------------------
__global__ __launch_bounds__(256) void k0_prep(
    const float* __restrict__ q, u16* __restrict__ qbf,
    const float* __restrict__ W0, const float* __restrict__ W1,
    const float* __restrict__ W2, const float* __restrict__ W3,
    u16* __restrict__ Wt) {
  __shared__ float t[32][33];
  int bx = blockIdx.x, tid = threadIdx.x;
  if (bx < 1024) {
    // ---- wtrans ----
    int m = bx >> 8, rem = bx & 255;
    int n0 = (rem & 15) * 32, k0 = (rem >> 4) * 32;
    const float* W = (m == 0) ? W0 : (m == 1) ? W1 : (m == 2) ? W2 : W3;
    int tx = tid & 31, ty = tid >> 5;
#pragma unroll
    for (int r = 0; r < 32; r += 8)
      t[ty + r][tx] = W[(size_t)(k0 + ty + r) * DIM + n0 + tx];
    __syncthreads();
    u16* o = Wt + (size_t)m * DIM * DIM;
#pragma unroll
    for (int r = 0; r < 32; r += 8)
      o[(size_t)(n0 + ty + r) * DIM + k0 + tx] = f2bfu(t[tx][ty + r]);
  } else {
    // ---- cvt q (2 float4 per thread) ----
    int i0 = ((bx - 1024) * 256 + tid) * 2;
#pragma unroll
    for (int u2 = 0; u2 < 2; ++u2) {
      float4 f = ((const float4*)q)[i0 + u2];
      ushort4 u;
      u.x = f2bfu(f.x); u.y = f2bfu(f.y); u.z = f2bfu(f.z); u.w = f2bfu(f.w);
      ((ushort4*)qbf)[i0 + u2] = u;
    }
  }
}

// ---------------------------------------------------------------------------
// K1: [0,768) gemm1 (XCD-aware bijective swizzle); [768,1792) ret_kv.
// MFMA-heavy gemm1 blocks co-schedule with latency-bound ret_kv blocks.
// ---------------------------------------------------------------------------
__global__ __launch_bounds__(256) void k1_gemm1_retkv(
    const u16* __restrict__ qbf, const u16* __restrict__ WtAll,
    const float* __restrict__ ba, const float* __restrict__ bb,
    const float* __restrict__ bg,
    u16* __restrict__ Ab16, u16* __restrict__ Bb16, u16* __restrict__ Gb16,
    const float* __restrict__ k, const float* __restrict__ v,
    u16* __restrict__ KVTb, u16* __restrict__ VTg, u16* __restrict__ kcb) {
  __shared__ __align__(16) u16 smem[TM * BK + TN * BK];  // 32 KB (both paths)
  int bx = blockIdx.x, tid = threadIdx.x;
  if (bx < 768) {
    // bijective: bx = r + 8*(nT + 12*s), mT = s*8 + r  (r<8, s<8, nT<12)
    int r = bx & 7, t6 = bx >> 3;
    int nT = t6 % 12, s = t6 / 12;
    int mT = (s << 3) | r;
    gemm_tile(nT, mT, qbf, WtAll, ba, bb, bg, Ab16, Bb16, Gb16,
              0b101, smem, smem + TM * BK, tid);
    return;
  }
  // ---- ret_kv ----
  int bx2 = bx - 768;
  int bh = bx2 & 31, c = bx2 >> 5;
  int b = bh >> 3, h = bh & 7;
  int wave = tid >> 6, lane = tid & 63;
  u16* VT = smem;                 // 64*SS u16
  u16* KT = smem + 64 * SS;       // 64*SS u16 (total 18.4 KB < 32 KB)
  size_t base = ((size_t)(b * TT + c * CC)) * DIM + h * DH;
  int row = tid >> 2, part = tid & 3, e0 = part * 16;
  float w = __powf(DECAY, (float)(63 - row));
  __align__(16) u16 krow[16];
  {
    const float4* vs = (const float4*)(v + base + (size_t)row * DIM + e0);
    const float4* ks = (const float4*)(k + base + (size_t)row * DIM + e0);
#pragma unroll
    for (int u4 = 0; u4 < 4; ++u4) {
      float4 fv = vs[u4], fk = ks[u4];
      VT[(e0 + u4 * 4 + 0) * SS + row] = f2bfu(fv.x);
      VT[(e0 + u4 * 4 + 1) * SS + row] = f2bfu(fv.y);
      VT[(e0 + u4 * 4 + 2) * SS + row] = f2bfu(fv.z);
      VT[(e0 + u4 * 4 + 3) * SS + row] = f2bfu(fv.w);
      u16 k0s = f2bfu(fk.x * w), k1s = f2bfu(fk.y * w);
      u16 k2s = f2bfu(fk.z * w), k3s = f2bfu(fk.w * w);
      KT[(e0 + u4 * 4 + 0) * SS + row] = k0s;
      KT[(e0 + u4 * 4 + 1) * SS + row] = k1s;
      KT[(e0 + u4 * 4 + 2) * SS + row] = k2s;
      KT[(e0 + u4 * 4 + 3) * SS + row] = k3s;
      krow[u4 * 4 + 0] = k0s; krow[u4 * 4 + 1] = k1s;
      krow[u4 * 4 + 2] = k2s; krow[u4 * 4 + 3] = k3s;
    }
  }
  {  // write scaled-K row-major compact (t-major)
    u16* kdst = kcb + (((size_t)bh * NC + c) * 64 + row) * 64 + e0;
    *(uint4*)kdst = *(const uint4*)&krow[0];
    *(uint4*)(kdst + 8) = *(const uint4*)&krow[8];
  }
  __syncthreads();
  {
    int e = row;
    u16* dst = VTg + ((size_t)bh * 64 + e) * TT + c * 64 + part * 16;
    *(uint4*)dst = *(const uint4*)&VT[e * SS + part * 16];
    *(uint4*)(dst + 8) = *(const uint4*)&VT[e * SS + part * 16 + 8];
  }
  int wm = (wave >> 1) * 32, wn = (wave & 1) * 32;
  int rowA = lane & 15, khalf = lane >> 4;
  f32x4 acc[2][2];
#pragma unroll
  for (int i = 0; i < 2; ++i)
#pragma unroll
    for (int j = 0; j < 2; ++j) acc[i][j] = (f32x4){0.f, 0.f, 0.f, 0.f};
#pragma unroll
  for (int k0 = 0; k0 < 2; ++k0) {
    int gk = k0 * 4 + khalf;
    bf16x8 af[2], bfr[2];
#pragma unroll
    for (int mi = 0; mi < 2; ++mi)
      af[mi] = *(const bf16x8*)&VT[(wm + mi * 16 + rowA) * SS + gk * 8];
#pragma unroll
    for (int ni = 0; ni < 2; ++ni)
      bfr[ni] = *(const bf16x8*)&KT[(wn + ni * 16 + rowA) * SS + gk * 8];
#pragma unroll
    for (int mi = 0; mi < 2; ++mi)
#pragma unroll
      for (int ni = 0; ni < 2; ++ni)
        acc[mi][ni] = __builtin_amdgcn_mfma_f32_16x16x32_bf16(
            af[mi], bfr[ni], acc[mi][ni], 0, 0, 0);
  }
  int cloc = lane & 15, rq = (lane >> 4) * 4;
  u16* o = KVTb + ((size_t)(c * BHN + bh)) * 4096;
#pragma unroll
  for (int mi = 0; mi < 2; ++mi)
#pragma unroll
    for (int r = 0; r < 4; ++r) {
      int e = wm + mi * 16 + rq + r;
#pragma unroll
      for (int ni = 0; ni < 2; ++ni)
        o[e * 64 + (wn + ni * 16 + cloc)] = f2bfu(acc[mi][ni][r]);
    }
}

// ---------------------------------------------------------------------------
// K2: [0,512) retscan; [512,1024) scan_part.
// ---------------------------------------------------------------------------
__global__ __launch_bounds__(256) void k2_retscan_part(
    const u16* __restrict__ KVTb, u16* __restrict__ Ptb,
    const u16* __restrict__ Ab16, const u16* __restrict__ Bb16,
    float2* __restrict__ SAB) {
  int bx = blockIdx.x, tid = threadIdx.x;
  if (bx < 512) {
    dev_retscan(bx, tid, KVTb, Ptb);
    return;
  }
  dev_part(bx - 512, tid, Ab16, Bb16, SAB);
}

// ---------------------------------------------------------------------------
// K3: [0,512) scan_apply HIGH-ci FIRST; [512,1536) ret_out (all 1024 units).
// ---------------------------------------------------------------------------
__global__ __launch_bounds__(256) void k3_apply_retout(
    const u16* __restrict__ Ab16, const u16* __restrict__ Bb16,
    const u16* __restrict__ g, const float2* __restrict__ SAB,
    u16* __restrict__ hg,
    const u16* __restrict__ qbf, const u16* __restrict__ kcb,
    const u16* __restrict__ VTg, const u16* __restrict__ Ptb,
    u16* __restrict__ routb) {
  __shared__ __align__(16) u16 Sa[64 * SS];
  __shared__ float dp[66];
  __shared__ float dpi[64];
  int bx = blockIdx.x, tid = threadIdx.x;
  if (bx < 512) {
    dev_apply(511 - bx, tid, Ab16, Bb16, g, SAB, hg);
    return;
  }
  dev_retout(bx - 512, tid, Sa, dp, dpi, qbf, kcb, VTg, Ptb, routb);
}

// ---------------------------------------------------------------------------
// K4: gemm2 (512 blocks, TN=64): out = (h*g) @ Wo + bo + r_out
// ---------------------------------------------------------------------------
__global__ __launch_bounds__(256) void k4_gemm2(
    const u16* __restrict__ hgbf, const u16* __restrict__ Wto,
    const float* __restrict__ bo, float* __restrict__ out,
    const u16* __restrict__ routb) {
  __shared__ __align__(16) u16 smem[TM * BK + 64 * BK];  // 24 KB
  int bx = blockIdx.x;
  // bijective: bx = r + 8*(nT + 8*s), mT = s*8 + r  (r<8, s<8, nT<8)
  int r = bx & 7, t6 = bx >> 3;
  int nT = t6 & 7, s = t6 >> 3;
  int mT = (s << 3) | r;
  gemm_tile64(nT, mT, hgbf, Wto, bo, out, routb,
              smem, smem + TM * BK, threadIdx.x);
}

// ---------------------------------------------------------------------------
extern "C" void kernel_launch(void* const* d_in, const int* in_sizes, int n_in,
                              void* d_out, int out_size, void* d_ws, size_t ws_size,
                              hipStream_t stream) {
  const float* q  = (const float*)d_in[0];
  const float* k  = (const float*)d_in[1];
  const float* v  = (const float*)d_in[2];
  const float* Wa = (const float*)d_in[3];
  const float* ba = (const float*)d_in[4];
  const float* Wb = (const float*)d_in[5];
  const float* bb = (const float*)d_in[6];
  const float* Wg = (const float*)d_in[7];
  const float* bg = (const float*)d_in[8];
  const float* Wo = (const float*)d_in[9];
  const float* bo = (const float*)d_in[10];
  float* out = (float*)d_out;

  const size_t NEL = (size_t)BB * TT * DIM;  // 4,194,304
  float2* SAB = (float2*)d_ws;               // 64 chunks x 2048 cols = 1 MB
  u16* up = (u16*)(SAB + (size_t)NSC * 2048);
  u16* Ab16  = up;  up += NEL;               // a bf16
  u16* Bb16  = up;  up += NEL;               // b bf16
  u16* Gb16  = up;  up += NEL;               // g bf16
  u16* qbf   = up;  up += NEL;               // q bf16
  u16* hgbf  = up;  up += NEL;               // h*g bf16
  u16* WtAll = up;  up += 4 * DIM * DIM;     // W^T bf16
  u16* KVTb  = up;  up += (size_t)NC * BHN * 4096;
  u16* Ptb   = up;  up += (size_t)NC * BHN * 4096;
  u16* VTg   = up;  up += (size_t)BHN * 64 * TT;
  u16* routb = up;  up += NEL;               // r_out bf16
  u16* kcb   = up;  up += (size_t)BHN * NC * 64 * 64;  // scaled K bf16, 8 MB

  k0_prep<<<3072, 256, 0, stream>>>(q, qbf, Wa, Wb, Wg, Wo, WtAll);

  k1_gemm1_retkv<<<1792, 256, 0, stream>>>(qbf, WtAll, ba, bb, bg,
                                           Ab16, Bb16, Gb16,
                                           k, v, KVTb, VTg, kcb);

  k2_retscan_part<<<1024, 256, 0, stream>>>(KVTb, Ptb, Ab16, Bb16, SAB);

  k3_apply_retout<<<1536, 256, 0, stream>>>(Ab16, Bb16, Gb16, SAB, hgbf,
                                            qbf, kcb, VTg, Ptb, routb);

  k4_gemm2<<<512, 256, 0, stream>>>(hgbf, WtAll + 3 * DIM * DIM,
                                    bo, out, routb);
}